// Round 25
// baseline (249.003 us; speedup 1.0000x reference)
//
#include <hip/hip_runtime.h>
#include <hip/hip_bf16.h>

#define D 64
#define MARGIN 8e-5f   // covers np-noise (1.6e-5) + 9-bit packing (~2e-6)
#define RB 8           // resolve batch: rows per block-pass (shares eT stream)

typedef __attribute__((ext_vector_type(8))) short bf16x8;
typedef __attribute__((ext_vector_type(4))) float f32x4;
typedef __attribute__((ext_vector_type(4))) unsigned uint4v;

// ---------------------------------------------------------------------------
// VectorQuantizer — 4-node: prep -> main(4-wave scan + last-block decide) ->
// resolve -> histperp. Harness ref = numpy-f32 recompute; argmin must
// bit-match np-f32 (xx pairwise-8 sum, sequential-d FMA sgemm, first-min).
// vq_main: R20's proven 4-wave KS=2 scan geometry (73us: 1024 blocks x 256
// thr, each scans K/2 codes for 256 rows; weak 4-wave barrier domain beats
// R21-24's 8-wave coupling by ~18us). split-bf16 MFMA proxy acc = dot -
// ee/2 (6-MFMA chain seeded C = -ee/2); tile-major codes LDS-staged double-
// buffered (T14) -> 1 VMEM/wave/tile; packed top-2 (low 9 mantissa bits =
// complemented local idx, med3+max). DECIDE EMBEDDED: both half-blocks emit
// packed planes + xx, threadfence, atomicAdd(gdone[group]); the SECOND
// block re-reads planes via device-scope atomic reads (cross-XCD-safe
// pattern, same as histperp counts) and runs decide + ballot list + plain
// lossA store (R13: no f64 atomics) + coalesced quantized write -> no
// epilogue node, no 8-wave coupling. vq_resolve: batched np-f32-exact, RB
// rows share ONE eT stream (R19). vq_histperp: 16-block LDS hist (R17:
// direct counts atomics serialize) + last-block finalize. R22 lesson:
// full-grid spin barriers are worse than boundaries; this election is
// per-group and spin-free.
// d_out (float): quantized[N*D] | loss[1] | indices[N] | perplexity[1]
// ws: counts u32[K] | done u32 | nunc u32 | pad | neh f32[K] | eenp f32[K]
//     | ehs bf16-tiles[K*256B] | eT f32[D*K] | list u32[N]
//     | m1p f32[2N] | m2p f32[2N] | xxp f32[N] | gdone u32[N/256]
//     | lossA f64[N/256] | lossR f64[128]
// ---------------------------------------------------------------------------

__device__ __forceinline__ float np_pairwise_sumsq64(const float* a) {
    float r[8];
#pragma unroll
    for (int j = 0; j < 8; ++j) r[j] = __fmul_rn(a[j], a[j]);
#pragma unroll
    for (int i = 8; i < 64; i += 8)
#pragma unroll
        for (int j = 0; j < 8; ++j)
            r[j] = __fadd_rn(r[j], __fmul_rn(a[i + j], a[i + j]));
    return __fadd_rn(
        __fadd_rn(__fadd_rn(r[0], r[1]), __fadd_rn(r[2], r[3])),
        __fadd_rn(__fadd_rn(r[4], r[5]), __fadd_rn(r[6], r[7])));
}

#define CVT8(F0, F1, H, L)                                                    \
    do {                                                                      \
        float _f[8] = {F0.x, F0.y, F0.z, F0.w, F1.x, F1.y, F1.z, F1.w};       \
        _Pragma("unroll") for (int _i = 0; _i < 8; ++_i) {                    \
            unsigned _u = __float_as_uint(_f[_i]);                            \
            unsigned _hb = (_u + 0x7fffu + ((_u >> 16) & 1u)) >> 16;          \
            float _hf = __uint_as_float(_hb << 16);                           \
            float _r = _f[_i] - _hf;                                          \
            unsigned _u2 = __float_as_uint(_r);                               \
            unsigned _lb = (_u2 + 0x7fffu + ((_u2 >> 16) & 1u)) >> 16;        \
            H[_i] = (short)_hb;                                               \
            L[_i] = (short)_lb;                                               \
        }                                                                     \
    } while (0)

// prep: [0,64) ehs tile-major; [64,68) sumsq; [68,324) eT; 324 zero counters
__global__ __launch_bounds__(256) void vq_prep_all(
    const float* __restrict__ emb, int K, int N,
    float* __restrict__ eenp, float* __restrict__ neh,
    unsigned short* __restrict__ ehs, float* __restrict__ eT,
    unsigned* __restrict__ counts, unsigned* __restrict__ done,
    unsigned* __restrict__ nunc, unsigned* __restrict__ gdone) {
    int b = blockIdx.x;
    if (b < 64) {
        int t = b * 256 + threadIdx.x;     // (tile, sec, lane): 16384 frags
        int tile = t >> 8, r = t & 255, s = r >> 6, l = r & 63;
        int sub = l & 15, grp = l >> 4;
        int k = tile * 16 + sub;
        int d0 = ((s & 1) << 5) + (grp << 3);
        const float* e = emb + (size_t)k * D + d0;
        float4 f0 = *(const float4*)e;
        float4 f1 = *(const float4*)(e + 4);
        bf16x8 h, lo;
        CVT8(f0, f1, h, lo);
        *(bf16x8*)(ehs + (size_t)t * 8) = (s >> 1) ? lo : h;  // s0,s1=eh s2,s3=el
    } else if (b < 68) {
        int k = (b - 64) * 256 + threadIdx.x;   // 1024 codes
        float s = np_pairwise_sumsq64(emb + (size_t)k * D);
        eenp[k] = s;
        neh[k] = -0.5f * s;
    } else if (b < 324) {
        int t = (b - 68) * 256 + threadIdx.x;   // 65536 = D*K, coalesced write
        int d = t / K, k = t - d * K;
        eT[t] = emb[(size_t)k * D + d];
    } else {
#pragma unroll
        for (int i = 0; i < 4; ++i) {
            int c = threadIdx.x + 256 * i;
            if (c < K) counts[c] = 0u;
        }
        int ng = N / 256;
        for (int i = threadIdx.x; i < ng; i += 256) gdone[i] = 0u;
        if (threadIdx.x == 0) { *done = 0u; *nunc = 0u; }
    }
}

// 4-wave scan (R20 geometry) + plane emit + last-block-of-group decide.
__global__ __launch_bounds__(256) void vq_main(
    const float* __restrict__ x, const unsigned short* __restrict__ ehs,
    const float* __restrict__ neh, const float* __restrict__ emb,
    int N, int K,
    float* __restrict__ m1p, float* __restrict__ m2p, float* __restrict__ xxp,
    unsigned* __restrict__ gdone,
    float* __restrict__ outq, float* __restrict__ outidx,
    double* __restrict__ lossA,
    unsigned* __restrict__ nunc, unsigned* __restrict__ list) {
    const int tid = threadIdx.x;
    const int lane = tid & 63;
    const int wid = tid >> 6;
    const int kslice = blockIdx.x & 1;
    const int rowblk = blockIdx.x >> 1;
    const int rows0 = rowblk * 256;
    const int row0 = rows0 + wid * 64;   // 64 rows/wave
    const int sub = lane & 15, grp = lane >> 4;
    const int g4 = grp << 2;
    const int k0 = kslice * (K >> 1);
    const int NT = (K >> 1) >> 4;        // 32 tiles in this half
    const int t0 = k0 >> 4;

    __shared__ __align__(16) unsigned short lds[2][2048];  // 2 bufs x 4KB
    __shared__ int sdec[256];
    __shared__ int select;
    __shared__ double ls[4];

    // persistent B frags: x rows, split bf16, 4 row-tiles x 2 k-slices.
    bf16x8 xh[4][2], xl[4][2];
    float xq[4];
#pragma unroll
    for (int rt = 0; rt < 4; ++rt) {
        xq[rt] = 0.f;
        const float* xrow = x + (((size_t)(row0 + (rt << 4) + sub)) << 6) + (grp << 3);
#pragma unroll
        for (int s = 0; s < 2; ++s) {
            float4 f0 = *(const float4*)(xrow + (s << 5));
            float4 f1 = *(const float4*)(xrow + (s << 5) + 4);
            xq[rt] = fmaf(f0.x, f0.x, xq[rt]); xq[rt] = fmaf(f0.y, f0.y, xq[rt]);
            xq[rt] = fmaf(f0.z, f0.z, xq[rt]); xq[rt] = fmaf(f0.w, f0.w, xq[rt]);
            xq[rt] = fmaf(f1.x, f1.x, xq[rt]); xq[rt] = fmaf(f1.y, f1.y, xq[rt]);
            xq[rt] = fmaf(f1.z, f1.z, xq[rt]); xq[rt] = fmaf(f1.w, f1.w, xq[rt]);
            CVT8(f0, f1, xh[rt][s], xl[rt][s]);
        }
    }
#pragma unroll
    for (int rt = 0; rt < 4; ++rt) {
        xq[rt] += __shfl_xor(xq[rt], 16);
        xq[rt] += __shfl_xor(xq[rt], 32);  // lane<16 holds full row xx
    }

    // packed top-2: low 9 mantissa bits = complemented half-local code idx
    float m1[4], m2[4];
#pragma unroll
    for (int rt = 0; rt < 4; ++rt) { m1[rt] = -3e38f; m2[rt] = -3e38f; }

    const unsigned short* sbase = ehs + ((size_t)t0 << 11);  // 2048 ush/tile
    const int slot = (wid << 9) + (lane << 3);               // ushort offset

    uint4v tmp = *(const uint4v*)(sbase + slot);             // tile 0
    *(uint4v*)&lds[0][slot] = tmp;
    __syncthreads();

    for (int t = 0; t < NT; ++t) {
        const int cur = t & 1;
        if (t + 1 < NT)  // T14: issue next-tile load before compute
            tmp = *(const uint4v*)(sbase + ((size_t)(t + 1) << 11) + slot);

        f32x4 cb = *(const f32x4*)(neh + k0 + (t << 4) + g4);
        const bf16x8* L = (const bf16x8*)&lds[cur][0];
        bf16x8 a0 = L[lane];        // eh d[0,32)
        bf16x8 a1 = L[64 + lane];   // eh d[32,64)
        bf16x8 a2 = L[128 + lane];  // el d[0,32)
        bf16x8 a3 = L[192 + lane];  // el d[32,64)

        f32x4 acc[4];
#pragma unroll
        for (int rt = 0; rt < 4; ++rt)
            acc[rt] = __builtin_amdgcn_mfma_f32_16x16x32_bf16(a0, xh[rt][0], cb, 0, 0, 0);
#pragma unroll
        for (int rt = 0; rt < 4; ++rt)
            acc[rt] = __builtin_amdgcn_mfma_f32_16x16x32_bf16(a2, xh[rt][0], acc[rt], 0, 0, 0);
#pragma unroll
        for (int rt = 0; rt < 4; ++rt)
            acc[rt] = __builtin_amdgcn_mfma_f32_16x16x32_bf16(a0, xl[rt][0], acc[rt], 0, 0, 0);
#pragma unroll
        for (int rt = 0; rt < 4; ++rt)
            acc[rt] = __builtin_amdgcn_mfma_f32_16x16x32_bf16(a1, xh[rt][1], acc[rt], 0, 0, 0);
#pragma unroll
        for (int rt = 0; rt < 4; ++rt)
            acc[rt] = __builtin_amdgcn_mfma_f32_16x16x32_bf16(a3, xh[rt][1], acc[rt], 0, 0, 0);
#pragma unroll
        for (int rt = 0; rt < 4; ++rt)
            acc[rt] = __builtin_amdgcn_mfma_f32_16x16x32_bf16(a1, xl[rt][1], acc[rt], 0, 0, 0);

        // packed top-2 update: 3 VALU/value (and_or + med3 + max)
        const int baset = 511 - (t << 4) - g4;
#pragma unroll
        for (int rt = 0; rt < 4; ++rt) {
#pragma unroll
            for (int j = 0; j < 4; ++j) {
                unsigned pv = (__float_as_uint(acc[rt][j]) & 0xFFFFFE00u)
                              | (unsigned)(baset - j);
                float p = __uint_as_float(pv);
                m2[rt] = fminf(fmaxf(p, m2[rt]), m1[rt]);  // med3(p,m2,m1)
                m1[rt] = fmaxf(p, m1[rt]);
            }
        }

        if (t + 1 < NT)  // T14: write-late into the other buffer
            *(uint4v*)&lds[cur ^ 1][slot] = tmp;
        __syncthreads();
    }

    // merge the 4 code-groups: pure min/max on packed values
#pragma unroll
    for (int rt = 0; rt < 4; ++rt) {
#pragma unroll
        for (int off = 16; off <= 32; off <<= 1) {
            float om1 = __shfl_xor(m1[rt], off);
            float om2 = __shfl_xor(m2[rt], off);
            float lo = fminf(m1[rt], om1);
            m1[rt] = fmaxf(m1[rt], om1);
            m2[rt] = fmaxf(lo, fmaxf(m2[rt], om2));
        }
    }

    // emit coalesced planes (lanes 0-15 own 16 consecutive rows per rt)
    if (lane < 16) {
#pragma unroll
        for (int rt = 0; rt < 4; ++rt) {
            size_t idx = (size_t)kslice * N + row0 + (rt << 4) + lane;
            m1p[idx] = m1[rt];
            m2p[idx] = m2[rt];
            if (kslice == 0) xxp[row0 + (rt << 4) + lane] = xq[rt];
        }
    }

    // election: second block of this row-group performs the decide
    __threadfence();
    __syncthreads();
    if (tid == 0) select = (int)atomicAdd(gdone + rowblk, 1u);
    __syncthreads();
    if (select == 0) return;  // first finisher exits

    // decide (device-scope atomic reads of planes: cross-XCD-safe)
    {
        const int r = rows0 + tid;
        float m1a = __uint_as_float(atomicAdd((unsigned*)&m1p[r], 0u));
        float m1b = __uint_as_float(atomicAdd((unsigned*)&m1p[(size_t)N + r], 0u));
        float m2a = __uint_as_float(atomicAdd((unsigned*)&m2p[r], 0u));
        float m2b = __uint_as_float(atomicAdd((unsigned*)&m2p[(size_t)N + r], 0u));
        float xxv = __uint_as_float(atomicAdd((unsigned*)&xxp[r], 0u));
        bool take = m1b > m1a;  // strict: equal packed bits -> MARGIN band
        float gm1 = fmaxf(m1a, m1b);
        float gm2 = fmaxf(fminf(m1a, m1b), fmaxf(m2a, m2b));
        int loc = 511 - (int)(__float_as_uint(gm1) & 511u);
        int k = (take ? (K >> 1) : 0) + loc;
        bool amb = 2.0f * (gm1 - gm2) < MARGIN;
        unsigned long long mask = __ballot(amb);
        int cnt = __popcll(mask);
        unsigned base = 0;
        if (lane == 0 && cnt) base = atomicAdd(nunc, (unsigned)cnt);
        base = __shfl(base, 0);
        int dec = k;
        double lpart = 0.0;
        if (amb) {
            int rank = __popcll(mask & ((1ull << lane) - 1ull));
            list[base + rank] = (unsigned)r;
            dec = -1;
        } else {
            outidx[r] = (float)dec;
            // strip 9 packed index bits, then ||x-e||^2 = xx - 2*m1
            float gm1v = __uint_as_float(__float_as_uint(gm1) & 0xFFFFFE00u);
            lpart = (double)(xxv - 2.0f * gm1v);
        }
        sdec[tid] = dec;
#pragma unroll
        for (int off = 32; off; off >>= 1) lpart += __shfl_down(lpart, off);
        if (lane == 0) ls[wid] = lpart;
    }
    __syncthreads();
    if (tid == 0)
        lossA[rowblk] = ls[0] + ls[1] + ls[2] + ls[3];  // plain store

    // quantized gather-write: wave-contiguous 1KB per pass, 16 passes
    const int chunk = tid & 15, rl = tid >> 4;  // 16 rows x 16 chunks
#pragma unroll
    for (int p = 0; p < 16; ++p) {
        int lr = p * 16 + rl;
        int dp = sdec[lr];
        if (dp >= 0) {
            float4 ev = *(const float4*)(emb + (size_t)dp * D + chunk * 4);
            *(float4*)(outq + (size_t)(rows0 + lr) * D + chunk * 4) = ev;
        }
    }
}

// batched np-f32-exact resolve: RB rows per block-pass share one eT stream
__global__ __launch_bounds__(256) void vq_resolve(
    const float* __restrict__ x, const float* __restrict__ emb,
    const float* __restrict__ eT, const float* __restrict__ eenp,
    int N, int K,
    float* __restrict__ outq, float* __restrict__ outidx,
    double* __restrict__ lossR,
    const unsigned* __restrict__ nunc, const unsigned* __restrict__ list) {
    const unsigned n = *nunc;
    const int tid = threadIdx.x;
    const int w = tid >> 6, l = tid & 63;
    const f32x4* eT4 = (const f32x4*)eT;  // [D][K/4]
    __shared__ float sxr[RB][64];
    __shared__ float sxx[RB];
    __shared__ float swm[RB][4];
    __shared__ int swi[RB][4];
    __shared__ int sres[RB];
    double lacc = 0.0;

    for (unsigned base = blockIdx.x * RB; base < n; base += gridDim.x * RB) {
        const int nb = (int)(n - base < (unsigned)RB ? n - base : (unsigned)RB);
#pragma unroll
        for (int i = tid; i < RB * 64; i += 256) {
            int r = i >> 6, d = i & 63;
            if (r < nb) sxr[r][d] = x[(size_t)list[base + r] * D + d];
        }
        __syncthreads();
        if (tid < nb) sxx[tid] = np_pairwise_sumsq64(&sxr[tid][0]);
        __syncthreads();

        f32x4 dt[RB];
#pragma unroll
        for (int r = 0; r < RB; ++r) dt[r] = (f32x4){0.f, 0.f, 0.f, 0.f};
#pragma unroll 4
        for (int d = 0; d < D; ++d) {
            f32x4 ev = eT4[(size_t)d * 256 + tid];
#pragma unroll
            for (int r = 0; r < RB; ++r) {
                float xv = sxr[r][d];
                dt[r][0] = __fmaf_rn(xv, ev[0], dt[r][0]);
                dt[r][1] = __fmaf_rn(xv, ev[1], dt[r][1]);
                dt[r][2] = __fmaf_rn(xv, ev[2], dt[r][2]);
                dt[r][3] = __fmaf_rn(xv, ev[3], dt[r][3]);
            }
        }

#pragma unroll
        for (int r = 0; r < RB; ++r) {
            if (r >= nb) break;
            float xx = sxx[r];
            float bm = 1e30f;
            int bi = 0;
#pragma unroll
            for (int jj = 0; jj < 4; ++jj) {
                int k = (tid << 2) + jj;  // ascending within thread
                float dist = __fsub_rn(__fadd_rn(xx, eenp[k]),
                                       __fmul_rn(2.0f, dt[r][jj]));
                if (dist < bm) { bm = dist; bi = k; }
            }
#pragma unroll
            for (int off = 1; off < 64; off <<= 1) {
                float ov = __shfl_xor(bm, off);
                int oi = __shfl_xor(bi, off);
                if (ov < bm || (ov == bm && oi < bi)) { bm = ov; bi = oi; }
            }
            if (l == 0) { swm[r][w] = bm; swi[r][w] = bi; }
        }
        __syncthreads();
        if (tid < nb) {  // thread r finalizes row r (ascending wave order)
            float fm = swm[tid][0];
            int fi = swi[tid][0];
#pragma unroll
            for (int ww = 1; ww < 4; ++ww) {
                float ov = swm[tid][ww];
                int oi = swi[tid][ww];
                if (ov < fm || (ov == fm && oi < fi)) { fm = ov; fi = oi; }
            }
            sres[tid] = fi;
            outidx[list[base + tid]] = (float)fi;
            lacc += (double)fm;
        }
        __syncthreads();
        for (int i = tid; i < RB * 64; i += 256) {
            int r = i >> 6, d = i & 63;
            if (r < nb)
                outq[(size_t)list[base + r] * D + d] =
                    emb[(size_t)sres[r] * D + d];
        }
        __syncthreads();
    }
#pragma unroll
    for (int off = 32; off; off >>= 1) lacc += __shfl_down(lacc, off);
    __shared__ double lsw;
    if (tid == 0) lsw = lacc;
    __syncthreads();
    if (tid == 0) lossR[blockIdx.x] = lsw;
}

// histogram of outidx via LDS (16 fat blocks) + last-block finalize
__global__ __launch_bounds__(256) void vq_histperp(
    const float* __restrict__ outidx, int N, int K,
    unsigned* __restrict__ counts, unsigned* __restrict__ done,
    const double* __restrict__ lossA, int nA,
    const double* __restrict__ lossR, int nR,
    float* __restrict__ out_loss, float* __restrict__ out_perp) {
    __shared__ unsigned h[1024];
    __shared__ unsigned rank_s;
#pragma unroll
    for (int i = 0; i < 4; ++i) h[threadIdx.x + 256 * i] = 0;
    __syncthreads();
    int per = N / gridDim.x;
    int base = blockIdx.x * per;
    for (int i = threadIdx.x; i < per; i += 256) {
        int k = (int)outidx[base + i];
        atomicAdd(&h[k], 1u);
    }
    __syncthreads();
#pragma unroll
    for (int i = 0; i < 4; ++i) {
        int b = threadIdx.x + 256 * i;
        unsigned v = h[b];
        if (b < K && v) atomicAdd(counts + b, v);
    }
    __threadfence();
    if (threadIdx.x == 0) rank_s = atomicAdd(done, 1u);
    __syncthreads();
    if (rank_s == gridDim.x - 1) {  // last block: counts complete
        double part = 0.0;
        for (int k = threadIdx.x; k < K; k += 256) {
            unsigned c = atomicAdd(counts + k, 0u);  // device-scope read
            double p = (double)c / (double)N;
            part += p * log(p + 1e-10);
        }
        double lsum = 0.0;
        for (int i = threadIdx.x; i < nA; i += 256) lsum += lossA[i];
        for (int i = threadIdx.x; i < nR; i += 256) lsum += lossR[i];
#pragma unroll
        for (int off = 32; off; off >>= 1) {
            part += __shfl_down(part, off);
            lsum += __shfl_down(lsum, off);
        }
        __shared__ double ls[4], ls2[4];
        if ((threadIdx.x & 63) == 0) {
            ls[threadIdx.x >> 6] = part;
            ls2[threadIdx.x >> 6] = lsum;
        }
        __syncthreads();
        if (threadIdx.x == 0) {
            double s = ls[0] + ls[1] + ls[2] + ls[3];
            double L = ls2[0] + ls2[1] + ls2[2] + ls2[3];
            *out_perp = (float)exp(-s);
            *out_loss = (float)(1.25 * (L / ((double)N * (double)D)));
        }
    }
}

extern "C" void kernel_launch(void* const* d_in, const int* in_sizes, int n_in,
                              void* d_out, int out_size, void* d_ws, size_t ws_size,
                              hipStream_t stream) {
    const float* x = (const float*)d_in[0];
    const float* emb = (const float*)d_in[1];
    int N = in_sizes[0] / D;
    int K = in_sizes[1] / D;

    float* outq = (float*)d_out;
    float* out_loss = outq + (size_t)N * D;
    float* outidx = out_loss + 1;
    float* out_perp = outidx + N;

    char* ws = (char*)d_ws;
    unsigned* counts = (unsigned*)ws;                          // K*4
    unsigned* done = (unsigned*)(ws + (size_t)K * 4);          // 4
    unsigned* nunc = (unsigned*)(ws + (size_t)K * 4 + 4);      // 4 (+8 pad)
    size_t off = (size_t)K * 4 + 16;
    float* neh = (float*)(ws + off);            off += (size_t)K * 4;
    float* eenp = (float*)(ws + off);           off += (size_t)K * 4;
    unsigned short* ehs = (unsigned short*)(ws + off);  off += (size_t)K * 256;
    float* eT = (float*)(ws + off);              off += (size_t)K * D * 4;
    unsigned* list = (unsigned*)(ws + off);      off += (size_t)N * 4;
    float* m1p = (float*)(ws + off);             off += (size_t)2 * N * 4;
    float* m2p = (float*)(ws + off);             off += (size_t)2 * N * 4;
    float* xxp = (float*)(ws + off);             off += (size_t)N * 4;
    int nG = N / 256;
    unsigned* gdone = (unsigned*)(ws + off);     off += (size_t)nG * 4;
    double* lossA = (double*)(ws + off);         off += (size_t)nG * 8;
    int nR = 128;
    double* lossR = (double*)(ws + off);         off += (size_t)nR * 8;

    // prep: 64 ehs + 4 sums + 256 eT + 1 zero-counters = 325 blocks
    vq_prep_all<<<325, 256, 0, stream>>>(emb, K, N, eenp, neh, ehs, eT,
                                         counts, done, nunc, gdone);
    vq_main<<<(N / 256) * 2, 256, 0, stream>>>(x, ehs, neh, emb, N, K,
                                               m1p, m2p, xxp, gdone,
                                               outq, outidx, lossA,
                                               nunc, list);
    vq_resolve<<<128, 256, 0, stream>>>(x, emb, eT, eenp, N, K,
                                        outq, outidx, lossR, nunc, list);
    vq_histperp<<<16, 256, 0, stream>>>(outidx, N, K, counts, done,
                                        lossA, nG, lossR, nR,
                                        out_loss, out_perp);
}

// Round 26
// 153.785 us; speedup vs baseline: 1.6192x; 1.6192x over previous
//
#include <hip/hip_runtime.h>
#include <hip/hip_bf16.h>

#define D 64
#define MARGIN 8e-5f   // covers np-noise (1.6e-5) + 9-bit packing (~2e-6)
#define RB 8           // resolve batch: rows per block-pass (shares eT stream)

typedef __attribute__((ext_vector_type(8))) short bf16x8;
typedef __attribute__((ext_vector_type(4))) float f32x4;
typedef __attribute__((ext_vector_type(4))) unsigned uint4v;

// ---------------------------------------------------------------------------
// VectorQuantizer — 4-node pipeline: prep -> main(scan+decide+write) ->
// resolve -> histperp. R24 configuration (best: 153.4us), reverted after R25
// (election + device-scope atomic READS on per-row path = 188us main; the
// R13 atomic lesson applies to reads too). Harness ref = numpy-f32
// recompute; argmin must bit-match np-f32 (xx pairwise-8 sum, sequential-d
// FMA sgemm, first-min). vq_main: 512-thr block = 8 waves (4 row-quads x 2
// k-halves); split-bf16 MFMA proxy acc = dot - ee/2 (6-MFMA chain seeded
// C = -ee/2), argmax(acc) == argmin(dist); tile-major codes LDS-staged,
// FOUR tiles per barrier (R23/R24: fewer barrier drains = -8us; 2 blocks/CU
// unchanged at 71KB LDS); packed top-2 (low 9 mantissa bits = complemented
// local idx, med3+max); halves merge in-LDS, decide, ballot+rank list (1 u32
// atomic/wave), plain lossA store (R13: NO f64 atomics — CAS loops),
// coalesced quantized write. vq_resolve: batched np-f32-exact, RB rows share
// ONE eT stream (R19 lesson). vq_histperp: 16-block LDS hist (R17 lesson:
// direct counts atomics serialize ~200us) + last-block finalize. Prep zeroes
// counters (no memset node). R22/R25 lesson: any intra-kernel cross-block
// sync (spin barrier, election, atomic-read planes) costs more than a clean
// kernel boundary (~12us).
// d_out (float): quantized[N*D] | loss[1] | indices[N] | perplexity[1]
// ws: counts u32[K] | done u32 | nunc u32 | pad | neh f32[K] | eenp f32[K]
//     | ehs bf16-tiles[K*256B] | eT f32[D*K] | list u32[N]
//     | lossA f64[N/256] | lossR f64[128]
// ---------------------------------------------------------------------------

__device__ __forceinline__ float np_pairwise_sumsq64(const float* a) {
    float r[8];
#pragma unroll
    for (int j = 0; j < 8; ++j) r[j] = __fmul_rn(a[j], a[j]);
#pragma unroll
    for (int i = 8; i < 64; i += 8)
#pragma unroll
        for (int j = 0; j < 8; ++j)
            r[j] = __fadd_rn(r[j], __fmul_rn(a[i + j], a[i + j]));
    return __fadd_rn(
        __fadd_rn(__fadd_rn(r[0], r[1]), __fadd_rn(r[2], r[3])),
        __fadd_rn(__fadd_rn(r[4], r[5]), __fadd_rn(r[6], r[7])));
}

#define CVT8(F0, F1, H, L)                                                    \
    do {                                                                      \
        float _f[8] = {F0.x, F0.y, F0.z, F0.w, F1.x, F1.y, F1.z, F1.w};       \
        _Pragma("unroll") for (int _i = 0; _i < 8; ++_i) {                    \
            unsigned _u = __float_as_uint(_f[_i]);                            \
            unsigned _hb = (_u + 0x7fffu + ((_u >> 16) & 1u)) >> 16;          \
            float _hf = __uint_as_float(_hb << 16);                           \
            float _r = _f[_i] - _hf;                                          \
            unsigned _u2 = __float_as_uint(_r);                               \
            unsigned _lb = (_u2 + 0x7fffu + ((_u2 >> 16) & 1u)) >> 16;        \
            H[_i] = (short)_hb;                                               \
            L[_i] = (short)_lb;                                               \
        }                                                                     \
    } while (0)

// prep: [0,64) ehs tile-major; [64,68) sumsq; [68,324) eT; 324 zero counters
__global__ __launch_bounds__(256) void vq_prep_all(
    const float* __restrict__ emb, int K,
    float* __restrict__ eenp, float* __restrict__ neh,
    unsigned short* __restrict__ ehs, float* __restrict__ eT,
    unsigned* __restrict__ counts, unsigned* __restrict__ done,
    unsigned* __restrict__ nunc) {
    int b = blockIdx.x;
    if (b < 64) {
        int t = b * 256 + threadIdx.x;     // (tile, sec, lane): 16384 frags
        int tile = t >> 8, r = t & 255, s = r >> 6, l = r & 63;
        int sub = l & 15, grp = l >> 4;
        int k = tile * 16 + sub;
        int d0 = ((s & 1) << 5) + (grp << 3);
        const float* e = emb + (size_t)k * D + d0;
        float4 f0 = *(const float4*)e;
        float4 f1 = *(const float4*)(e + 4);
        bf16x8 h, lo;
        CVT8(f0, f1, h, lo);
        *(bf16x8*)(ehs + (size_t)t * 8) = (s >> 1) ? lo : h;  // s0,s1=eh s2,s3=el
    } else if (b < 68) {
        int k = (b - 64) * 256 + threadIdx.x;   // 1024 codes
        float s = np_pairwise_sumsq64(emb + (size_t)k * D);
        eenp[k] = s;
        neh[k] = -0.5f * s;
    } else if (b < 324) {
        int t = (b - 68) * 256 + threadIdx.x;   // 65536 = D*K, coalesced write
        int d = t / K, k = t - d * K;
        eT[t] = emb[(size_t)k * D + d];
    } else {
#pragma unroll
        for (int i = 0; i < 4; ++i) {
            int c = threadIdx.x + 256 * i;
            if (c < K) counts[c] = 0u;
        }
        if (threadIdx.x == 0) { *done = 0u; *nunc = 0u; }
    }
}

// one 16-code tile's worth of MFMA + packed top-2 (on LDS base L)
#define TILE_STEP(L, TT)                                                      \
    do {                                                                      \
        f32x4 cb = *(const f32x4*)(neh + k0 + ((TT) << 4) + g4);              \
        bf16x8 a0 = (L)[lane];                                                \
        bf16x8 a1 = (L)[64 + lane];                                           \
        bf16x8 a2 = (L)[128 + lane];                                          \
        bf16x8 a3 = (L)[192 + lane];                                          \
        f32x4 acc[4];                                                         \
        _Pragma("unroll") for (int rt = 0; rt < 4; ++rt)                      \
            acc[rt] = __builtin_amdgcn_mfma_f32_16x16x32_bf16(a0, xh[rt][0], cb, 0, 0, 0); \
        _Pragma("unroll") for (int rt = 0; rt < 4; ++rt)                      \
            acc[rt] = __builtin_amdgcn_mfma_f32_16x16x32_bf16(a2, xh[rt][0], acc[rt], 0, 0, 0); \
        _Pragma("unroll") for (int rt = 0; rt < 4; ++rt)                      \
            acc[rt] = __builtin_amdgcn_mfma_f32_16x16x32_bf16(a0, xl[rt][0], acc[rt], 0, 0, 0); \
        _Pragma("unroll") for (int rt = 0; rt < 4; ++rt)                      \
            acc[rt] = __builtin_amdgcn_mfma_f32_16x16x32_bf16(a1, xh[rt][1], acc[rt], 0, 0, 0); \
        _Pragma("unroll") for (int rt = 0; rt < 4; ++rt)                      \
            acc[rt] = __builtin_amdgcn_mfma_f32_16x16x32_bf16(a3, xh[rt][1], acc[rt], 0, 0, 0); \
        _Pragma("unroll") for (int rt = 0; rt < 4; ++rt)                      \
            acc[rt] = __builtin_amdgcn_mfma_f32_16x16x32_bf16(a1, xl[rt][1], acc[rt], 0, 0, 0); \
        const int baset = 511 - ((TT) << 4) - g4;                             \
        _Pragma("unroll") for (int rt = 0; rt < 4; ++rt) {                    \
            _Pragma("unroll") for (int j = 0; j < 4; ++j) {                   \
                unsigned pv = (__float_as_uint(acc[rt][j]) & 0xFFFFFE00u)     \
                              | (unsigned)(baset - j);                        \
                float p = __uint_as_float(pv);                                \
                m2[rt] = fminf(fmaxf(p, m2[rt]), m1[rt]);                     \
                m1[rt] = fmaxf(p, m1[rt]);                                    \
            }                                                                 \
        }                                                                     \
    } while (0)

// fused scan + decide + quantized write. 512 threads: 8 waves = 4 row-quads
// x 2 k-halves. 256 rows per block. FOUR tiles per barrier.
__global__ __launch_bounds__(512) void vq_main(
    const float* __restrict__ x, const unsigned short* __restrict__ ehs,
    const float* __restrict__ neh, const float* __restrict__ emb,
    int N, int K,
    float* __restrict__ outq, float* __restrict__ outidx,
    double* __restrict__ lossA,
    unsigned* __restrict__ nunc, unsigned* __restrict__ list) {
    const int tid = threadIdx.x;
    const int lane = tid & 63;
    const int wid = tid >> 6;
    const int half = wid >> 2;           // k-slice 0/1
    const int wq = wid & 3;              // row quad
    const int rows0 = blockIdx.x * 256;
    const int row0 = rows0 + wq * 64;    // 64 rows/wave
    const int sub = lane & 15, grp = lane >> 4;
    const int g4 = grp << 2;
    const int k0 = half * (K >> 1);
    const int NT = (K >> 1) >> 4;        // 32 tiles per half
    const int t0 = k0 >> 4;

    // [half][buf][4 tiles x 2048 ush] = 64KB; grid gives 2 blocks/CU anyway
    __shared__ __align__(16) unsigned short lds[2][2][8192];
    __shared__ float sm1[2][256], sm2[2][256], sxx[256];
    __shared__ int sdec[256];
    __shared__ double ls[4];

    bf16x8 xh[4][2], xl[4][2];
    float xq[4];
#pragma unroll
    for (int rt = 0; rt < 4; ++rt) {
        xq[rt] = 0.f;
        const float* xrow = x + (((size_t)(row0 + (rt << 4) + sub)) << 6) + (grp << 3);
#pragma unroll
        for (int s = 0; s < 2; ++s) {
            float4 f0 = *(const float4*)(xrow + (s << 5));
            float4 f1 = *(const float4*)(xrow + (s << 5) + 4);
            xq[rt] = fmaf(f0.x, f0.x, xq[rt]); xq[rt] = fmaf(f0.y, f0.y, xq[rt]);
            xq[rt] = fmaf(f0.z, f0.z, xq[rt]); xq[rt] = fmaf(f0.w, f0.w, xq[rt]);
            xq[rt] = fmaf(f1.x, f1.x, xq[rt]); xq[rt] = fmaf(f1.y, f1.y, xq[rt]);
            xq[rt] = fmaf(f1.z, f1.z, xq[rt]); xq[rt] = fmaf(f1.w, f1.w, xq[rt]);
            CVT8(f0, f1, xh[rt][s], xl[rt][s]);
        }
    }
#pragma unroll
    for (int rt = 0; rt < 4; ++rt) {
        xq[rt] += __shfl_xor(xq[rt], 16);
        xq[rt] += __shfl_xor(xq[rt], 32);  // lane<16 holds full row xx
    }

    float m1[4], m2[4];
#pragma unroll
    for (int rt = 0; rt < 4; ++rt) { m1[rt] = -3e38f; m2[rt] = -3e38f; }

    const unsigned short* sbase = ehs + ((size_t)t0 << 11);  // 2048 ush/tile
    const int slot = (wq << 9) + (lane << 3);                // ushort offset

    // prologue: stage tiles 0..3 into buf 0
    {
#pragma unroll
        for (int q = 0; q < 4; ++q) {
            uint4v p = *(const uint4v*)(sbase + ((size_t)q << 11) + slot);
            *(uint4v*)&lds[half][0][(q << 11) + slot] = p;
        }
    }
    __syncthreads();

    for (int t = 0; t < NT; t += 4) {
        const int cur = (t >> 2) & 1;
        uint4v n0, n1, n2, n3;
        if (t + 4 < NT) {  // T14: issue next-quad loads before compute
            n0 = *(const uint4v*)(sbase + ((size_t)(t + 4) << 11) + slot);
            n1 = *(const uint4v*)(sbase + ((size_t)(t + 5) << 11) + slot);
            n2 = *(const uint4v*)(sbase + ((size_t)(t + 6) << 11) + slot);
            n3 = *(const uint4v*)(sbase + ((size_t)(t + 7) << 11) + slot);
        }
        const bf16x8* L0 = (const bf16x8*)&lds[half][cur][0];
        const bf16x8* L1 = (const bf16x8*)&lds[half][cur][2048];
        const bf16x8* L2 = (const bf16x8*)&lds[half][cur][4096];
        const bf16x8* L3 = (const bf16x8*)&lds[half][cur][6144];
        TILE_STEP(L0, t);
        TILE_STEP(L1, t + 1);
        TILE_STEP(L2, t + 2);
        TILE_STEP(L3, t + 3);
        if (t + 4 < NT) {  // write-late into the other buffer
            *(uint4v*)&lds[half][cur ^ 1][slot] = n0;
            *(uint4v*)&lds[half][cur ^ 1][2048 + slot] = n1;
            *(uint4v*)&lds[half][cur ^ 1][4096 + slot] = n2;
            *(uint4v*)&lds[half][cur ^ 1][6144 + slot] = n3;
        }
        __syncthreads();
    }

    // merge the 4 code-groups: pure min/max on packed values
#pragma unroll
    for (int rt = 0; rt < 4; ++rt) {
#pragma unroll
        for (int off = 16; off <= 32; off <<= 1) {
            float om1 = __shfl_xor(m1[rt], off);
            float om2 = __shfl_xor(m2[rt], off);
            float lo = fminf(m1[rt], om1);
            m1[rt] = fmaxf(m1[rt], om1);
            m2[rt] = fmaxf(lo, fmaxf(m2[rt], om2));
        }
    }

    // per-half results -> LDS (lanes 0-15 own 16 consecutive rows per rt)
    if (lane < 16) {
#pragma unroll
        for (int rt = 0; rt < 4; ++rt) {
            int lr = wq * 64 + (rt << 4) + lane;
            sm1[half][lr] = m1[rt];
            sm2[half][lr] = m2[rt];
            if (half == 0) sxx[lr] = xq[rt];
        }
    }
    __syncthreads();

    // decide: waves 0-3, thread lr<256 merges the two halves for local row lr
    if (tid < 256) {
        const int lr = tid;
        const int r = rows0 + lr;
        float m1a = sm1[0][lr], m1b = sm1[1][lr];
        float m2a = sm2[0][lr], m2b = sm2[1][lr];
        bool take = m1b > m1a;  // strict: equal high-bit ties -> MARGIN band
        float gm1 = fmaxf(m1a, m1b);
        float gm2 = fmaxf(fminf(m1a, m1b), fmaxf(m2a, m2b));
        int loc = 511 - (int)(__float_as_uint(gm1) & 511u);
        int k = (take ? (K >> 1) : 0) + loc;
        bool amb = 2.0f * (gm1 - gm2) < MARGIN;
        unsigned long long mask = __ballot(amb);
        int cnt = __popcll(mask);
        unsigned base = 0;
        if (lane == 0 && cnt) base = atomicAdd(nunc, (unsigned)cnt);
        base = __shfl(base, 0);
        int dec = k;
        double lpart = 0.0;
        if (amb) {
            int rank = __popcll(mask & ((1ull << lane) - 1ull));
            list[base + rank] = (unsigned)r;
            dec = -1;
        } else {
            outidx[r] = (float)dec;
            // strip 9 packed index bits, then ||x-e||^2 = xx - 2*m1
            float gm1v = __uint_as_float(__float_as_uint(gm1) & 0xFFFFFE00u);
            lpart = (double)(sxx[lr] - 2.0f * gm1v);
        }
        sdec[lr] = dec;
#pragma unroll
        for (int off = 32; off; off >>= 1) lpart += __shfl_down(lpart, off);
        if (lane == 0) ls[wid] = lpart;
    }
    __syncthreads();
    if (tid == 0)
        lossA[blockIdx.x] = ls[0] + ls[1] + ls[2] + ls[3];  // plain store

    // quantized gather-write: 512 threads, wave-contiguous 1KB per pass
    const int chunk = tid & 15, rl = tid >> 4;  // 32 rows x 16 chunks
#pragma unroll
    for (int p = 0; p < 8; ++p) {
        int lr = p * 32 + rl;
        int dp = sdec[lr];
        if (dp >= 0) {
            float4 ev = *(const float4*)(emb + (size_t)dp * D + chunk * 4);
            *(float4*)(outq + (size_t)(rows0 + lr) * D + chunk * 4) = ev;
        }
    }
}

// batched np-f32-exact resolve: RB rows per block-pass share one eT stream
__global__ __launch_bounds__(256) void vq_resolve(
    const float* __restrict__ x, const float* __restrict__ emb,
    const float* __restrict__ eT, const float* __restrict__ eenp,
    int N, int K,
    float* __restrict__ outq, float* __restrict__ outidx,
    double* __restrict__ lossR,
    const unsigned* __restrict__ nunc, const unsigned* __restrict__ list) {
    const unsigned n = *nunc;
    const int tid = threadIdx.x;
    const int w = tid >> 6, l = tid & 63;
    const f32x4* eT4 = (const f32x4*)eT;  // [D][K/4]
    __shared__ float sxr[RB][64];
    __shared__ float sxx[RB];
    __shared__ float swm[RB][4];
    __shared__ int swi[RB][4];
    __shared__ int sres[RB];
    double lacc = 0.0;

    for (unsigned base = blockIdx.x * RB; base < n; base += gridDim.x * RB) {
        const int nb = (int)(n - base < (unsigned)RB ? n - base : (unsigned)RB);
#pragma unroll
        for (int i = tid; i < RB * 64; i += 256) {
            int r = i >> 6, d = i & 63;
            if (r < nb) sxr[r][d] = x[(size_t)list[base + r] * D + d];
        }
        __syncthreads();
        if (tid < nb) sxx[tid] = np_pairwise_sumsq64(&sxr[tid][0]);
        __syncthreads();

        f32x4 dt[RB];
#pragma unroll
        for (int r = 0; r < RB; ++r) dt[r] = (f32x4){0.f, 0.f, 0.f, 0.f};
#pragma unroll 4
        for (int d = 0; d < D; ++d) {
            f32x4 ev = eT4[(size_t)d * 256 + tid];
#pragma unroll
            for (int r = 0; r < RB; ++r) {
                float xv = sxr[r][d];
                dt[r][0] = __fmaf_rn(xv, ev[0], dt[r][0]);
                dt[r][1] = __fmaf_rn(xv, ev[1], dt[r][1]);
                dt[r][2] = __fmaf_rn(xv, ev[2], dt[r][2]);
                dt[r][3] = __fmaf_rn(xv, ev[3], dt[r][3]);
            }
        }

#pragma unroll
        for (int r = 0; r < RB; ++r) {
            if (r >= nb) break;
            float xx = sxx[r];
            float bm = 1e30f;
            int bi = 0;
#pragma unroll
            for (int jj = 0; jj < 4; ++jj) {
                int k = (tid << 2) + jj;  // ascending within thread
                float dist = __fsub_rn(__fadd_rn(xx, eenp[k]),
                                       __fmul_rn(2.0f, dt[r][jj]));
                if (dist < bm) { bm = dist; bi = k; }
            }
#pragma unroll
            for (int off = 1; off < 64; off <<= 1) {
                float ov = __shfl_xor(bm, off);
                int oi = __shfl_xor(bi, off);
                if (ov < bm || (ov == bm && oi < bi)) { bm = ov; bi = oi; }
            }
            if (l == 0) { swm[r][w] = bm; swi[r][w] = bi; }
        }
        __syncthreads();
        if (tid < nb) {  // thread r finalizes row r (ascending wave order)
            float fm = swm[tid][0];
            int fi = swi[tid][0];
#pragma unroll
            for (int ww = 1; ww < 4; ++ww) {
                float ov = swm[tid][ww];
                int oi = swi[tid][ww];
                if (ov < fm || (ov == fm && oi < fi)) { fm = ov; fi = oi; }
            }
            sres[tid] = fi;
            outidx[list[base + tid]] = (float)fi;
            lacc += (double)fm;
        }
        __syncthreads();
        for (int i = tid; i < RB * 64; i += 256) {
            int r = i >> 6, d = i & 63;
            if (r < nb)
                outq[(size_t)list[base + r] * D + d] =
                    emb[(size_t)sres[r] * D + d];
        }
        __syncthreads();
    }
#pragma unroll
    for (int off = 32; off; off >>= 1) lacc += __shfl_down(lacc, off);
    __shared__ double lsw;
    if (tid == 0) lsw = lacc;
    __syncthreads();
    if (tid == 0) lossR[blockIdx.x] = lsw;
}

// histogram of outidx via LDS (16 fat blocks) + last-block finalize
__global__ __launch_bounds__(256) void vq_histperp(
    const float* __restrict__ outidx, int N, int K,
    unsigned* __restrict__ counts, unsigned* __restrict__ done,
    const double* __restrict__ lossA, int nA,
    const double* __restrict__ lossR, int nR,
    float* __restrict__ out_loss, float* __restrict__ out_perp) {
    __shared__ unsigned h[1024];
    __shared__ unsigned rank_s;
#pragma unroll
    for (int i = 0; i < 4; ++i) h[threadIdx.x + 256 * i] = 0;
    __syncthreads();
    int per = N / gridDim.x;
    int base = blockIdx.x * per;
    for (int i = threadIdx.x; i < per; i += 256) {
        int k = (int)outidx[base + i];
        atomicAdd(&h[k], 1u);
    }
    __syncthreads();
#pragma unroll
    for (int i = 0; i < 4; ++i) {
        int b = threadIdx.x + 256 * i;
        unsigned v = h[b];
        if (b < K && v) atomicAdd(counts + b, v);
    }
    __threadfence();
    if (threadIdx.x == 0) rank_s = atomicAdd(done, 1u);
    __syncthreads();
    if (rank_s == gridDim.x - 1) {  // last block: counts complete
        double part = 0.0;
        for (int k = threadIdx.x; k < K; k += 256) {
            unsigned c = atomicAdd(counts + k, 0u);  // device-scope read
            double p = (double)c / (double)N;
            part += p * log(p + 1e-10);
        }
        double lsum = 0.0;
        for (int i = threadIdx.x; i < nA; i += 256) lsum += lossA[i];
        for (int i = threadIdx.x; i < nR; i += 256) lsum += lossR[i];
#pragma unroll
        for (int off = 32; off; off >>= 1) {
            part += __shfl_down(part, off);
            lsum += __shfl_down(lsum, off);
        }
        __shared__ double ls[4], ls2[4];
        if ((threadIdx.x & 63) == 0) {
            ls[threadIdx.x >> 6] = part;
            ls2[threadIdx.x >> 6] = lsum;
        }
        __syncthreads();
        if (threadIdx.x == 0) {
            double s = ls[0] + ls[1] + ls[2] + ls[3];
            double L = ls2[0] + ls2[1] + ls2[2] + ls2[3];
            *out_perp = (float)exp(-s);
            *out_loss = (float)(1.25 * (L / ((double)N * (double)D)));
        }
    }
}

extern "C" void kernel_launch(void* const* d_in, const int* in_sizes, int n_in,
                              void* d_out, int out_size, void* d_ws, size_t ws_size,
                              hipStream_t stream) {
    const float* x = (const float*)d_in[0];
    const float* emb = (const float*)d_in[1];
    int N = in_sizes[0] / D;
    int K = in_sizes[1] / D;

    float* outq = (float*)d_out;
    float* out_loss = outq + (size_t)N * D;
    float* outidx = out_loss + 1;
    float* out_perp = outidx + N;

    char* ws = (char*)d_ws;
    unsigned* counts = (unsigned*)ws;                          // K*4
    unsigned* done = (unsigned*)(ws + (size_t)K * 4);          // 4
    unsigned* nunc = (unsigned*)(ws + (size_t)K * 4 + 4);      // 4 (+8 pad)
    size_t off = (size_t)K * 4 + 16;
    float* neh = (float*)(ws + off);            off += (size_t)K * 4;
    float* eenp = (float*)(ws + off);           off += (size_t)K * 4;
    unsigned short* ehs = (unsigned short*)(ws + off);  off += (size_t)K * 256;
    float* eT = (float*)(ws + off);              off += (size_t)K * D * 4;
    unsigned* list = (unsigned*)(ws + off);      off += (size_t)N * 4;
    int nA = N / 256, nR = 128;
    double* lossA = (double*)(ws + off);         off += (size_t)nA * 8;
    double* lossR = (double*)(ws + off);         off += (size_t)nR * 8;

    // prep: 64 ehs + 4 sums + 256 eT + 1 zero-counters = 325 blocks
    vq_prep_all<<<325, 256, 0, stream>>>(emb, K, eenp, neh, ehs, eT,
                                         counts, done, nunc);
    vq_main<<<N / 256, 512, 0, stream>>>(x, ehs, neh, emb, N, K,
                                         outq, outidx, lossA, nunc, list);
    vq_resolve<<<128, 256, 0, stream>>>(x, emb, eT, eenp, N, K,
                                        outq, outidx, lossR, nunc, list);
    vq_histperp<<<16, 256, 0, stream>>>(outidx, N, K, counts, done,
                                        lossA, nA, lossR, nR,
                                        out_loss, out_perp);
}

// Round 27
// 148.385 us; speedup vs baseline: 1.6781x; 1.0364x over previous
//
#include <hip/hip_runtime.h>
#include <hip/hip_bf16.h>

#define D 64
#define MARGIN 8e-5f   // covers np-noise (1.6e-5) + 9-bit packing (~2e-6)
#define RB 8           // resolve batch: rows per block-pass (shares eT stream)

typedef __attribute__((ext_vector_type(8))) short bf16x8;
typedef __attribute__((ext_vector_type(4))) float f32x4;
typedef __attribute__((ext_vector_type(4))) unsigned uint4v;

// ---------------------------------------------------------------------------
// VectorQuantizer — R24/R26 structure (153.4us best) + global_load_lds
// staging (async direct-to-LDS, removes register round-trip + ds_writes;
// layout is exactly the wave-uniform-base + lane*16B shape the instruction
// requires). 4-node pipeline: prep -> main(scan+decide+write) -> resolve ->
// histperp. Harness ref = numpy-f32 recompute; argmin must bit-match np-f32
// (xx pairwise-8 sum, sequential-d FMA sgemm, first-min). vq_main: 512-thr
// block = 8 waves (4 row-quads x 2 k-halves); split-bf16 MFMA proxy acc =
// dot - ee/2 (6-MFMA chain seeded C = -ee/2); tile-major codes, FOUR tiles
// per barrier (R23/R24); packed top-2 (low 9 mantissa bits = complemented
// local idx, med3+max); in-LDS half merge, decide, ballot+rank list, plain
// lossA store (R13: no f64 atomics), coalesced quantized write. vq_resolve:
// batched np-f32-exact, RB rows share ONE eT stream (R19). vq_histperp:
// 16-block LDS hist (R17) + last-block finalize. R22/R25: no intra-kernel
// cross-block sync. Prep zeroes counters.
// d_out (float): quantized[N*D] | loss[1] | indices[N] | perplexity[1]
// ws: counts u32[K] | done u32 | nunc u32 | pad | neh f32[K] | eenp f32[K]
//     | ehs bf16-tiles[K*256B] | eT f32[D*K] | list u32[N]
//     | lossA f64[N/256] | lossR f64[128]
// ---------------------------------------------------------------------------

__device__ __forceinline__ float np_pairwise_sumsq64(const float* a) {
    float r[8];
#pragma unroll
    for (int j = 0; j < 8; ++j) r[j] = __fmul_rn(a[j], a[j]);
#pragma unroll
    for (int i = 8; i < 64; i += 8)
#pragma unroll
        for (int j = 0; j < 8; ++j)
            r[j] = __fadd_rn(r[j], __fmul_rn(a[i + j], a[i + j]));
    return __fadd_rn(
        __fadd_rn(__fadd_rn(r[0], r[1]), __fadd_rn(r[2], r[3])),
        __fadd_rn(__fadd_rn(r[4], r[5]), __fadd_rn(r[6], r[7])));
}

#define CVT8(F0, F1, H, L)                                                    \
    do {                                                                      \
        float _f[8] = {F0.x, F0.y, F0.z, F0.w, F1.x, F1.y, F1.z, F1.w};       \
        _Pragma("unroll") for (int _i = 0; _i < 8; ++_i) {                    \
            unsigned _u = __float_as_uint(_f[_i]);                            \
            unsigned _hb = (_u + 0x7fffu + ((_u >> 16) & 1u)) >> 16;          \
            float _hf = __uint_as_float(_hb << 16);                           \
            float _r = _f[_i] - _hf;                                          \
            unsigned _u2 = __float_as_uint(_r);                               \
            unsigned _lb = (_u2 + 0x7fffu + ((_u2 >> 16) & 1u)) >> 16;        \
            H[_i] = (short)_hb;                                               \
            L[_i] = (short)_lb;                                               \
        }                                                                     \
    } while (0)

// async global->LDS, 16B per lane; LDS dest = wave-uniform base + lane*16
#define GLL16(GS, LD)                                                         \
    __builtin_amdgcn_global_load_lds(                                         \
        (const __attribute__((address_space(1))) unsigned int*)(GS),          \
        (__attribute__((address_space(3))) unsigned int*)(LD), 16, 0, 0)

// prep: [0,64) ehs tile-major; [64,68) sumsq; [68,324) eT; 324 zero counters
__global__ __launch_bounds__(256) void vq_prep_all(
    const float* __restrict__ emb, int K,
    float* __restrict__ eenp, float* __restrict__ neh,
    unsigned short* __restrict__ ehs, float* __restrict__ eT,
    unsigned* __restrict__ counts, unsigned* __restrict__ done,
    unsigned* __restrict__ nunc) {
    int b = blockIdx.x;
    if (b < 64) {
        int t = b * 256 + threadIdx.x;     // (tile, sec, lane): 16384 frags
        int tile = t >> 8, r = t & 255, s = r >> 6, l = r & 63;
        int sub = l & 15, grp = l >> 4;
        int k = tile * 16 + sub;
        int d0 = ((s & 1) << 5) + (grp << 3);
        const float* e = emb + (size_t)k * D + d0;
        float4 f0 = *(const float4*)e;
        float4 f1 = *(const float4*)(e + 4);
        bf16x8 h, lo;
        CVT8(f0, f1, h, lo);
        *(bf16x8*)(ehs + (size_t)t * 8) = (s >> 1) ? lo : h;  // s0,s1=eh s2,s3=el
    } else if (b < 68) {
        int k = (b - 64) * 256 + threadIdx.x;   // 1024 codes
        float s = np_pairwise_sumsq64(emb + (size_t)k * D);
        eenp[k] = s;
        neh[k] = -0.5f * s;
    } else if (b < 324) {
        int t = (b - 68) * 256 + threadIdx.x;   // 65536 = D*K, coalesced write
        int d = t / K, k = t - d * K;
        eT[t] = emb[(size_t)k * D + d];
    } else {
#pragma unroll
        for (int i = 0; i < 4; ++i) {
            int c = threadIdx.x + 256 * i;
            if (c < K) counts[c] = 0u;
        }
        if (threadIdx.x == 0) { *done = 0u; *nunc = 0u; }
    }
}

// one 16-code tile's worth of MFMA + packed top-2 (on LDS base L)
#define TILE_STEP(L, TT)                                                      \
    do {                                                                      \
        f32x4 cb = *(const f32x4*)(neh + k0 + ((TT) << 4) + g4);              \
        bf16x8 a0 = (L)[lane];                                                \
        bf16x8 a1 = (L)[64 + lane];                                           \
        bf16x8 a2 = (L)[128 + lane];                                          \
        bf16x8 a3 = (L)[192 + lane];                                          \
        f32x4 acc[4];                                                         \
        _Pragma("unroll") for (int rt = 0; rt < 4; ++rt)                      \
            acc[rt] = __builtin_amdgcn_mfma_f32_16x16x32_bf16(a0, xh[rt][0], cb, 0, 0, 0); \
        _Pragma("unroll") for (int rt = 0; rt < 4; ++rt)                      \
            acc[rt] = __builtin_amdgcn_mfma_f32_16x16x32_bf16(a2, xh[rt][0], acc[rt], 0, 0, 0); \
        _Pragma("unroll") for (int rt = 0; rt < 4; ++rt)                      \
            acc[rt] = __builtin_amdgcn_mfma_f32_16x16x32_bf16(a0, xl[rt][0], acc[rt], 0, 0, 0); \
        _Pragma("unroll") for (int rt = 0; rt < 4; ++rt)                      \
            acc[rt] = __builtin_amdgcn_mfma_f32_16x16x32_bf16(a1, xh[rt][1], acc[rt], 0, 0, 0); \
        _Pragma("unroll") for (int rt = 0; rt < 4; ++rt)                      \
            acc[rt] = __builtin_amdgcn_mfma_f32_16x16x32_bf16(a3, xh[rt][1], acc[rt], 0, 0, 0); \
        _Pragma("unroll") for (int rt = 0; rt < 4; ++rt)                      \
            acc[rt] = __builtin_amdgcn_mfma_f32_16x16x32_bf16(a1, xl[rt][1], acc[rt], 0, 0, 0); \
        const int baset = 511 - ((TT) << 4) - g4;                             \
        _Pragma("unroll") for (int rt = 0; rt < 4; ++rt) {                    \
            _Pragma("unroll") for (int j = 0; j < 4; ++j) {                   \
                unsigned pv = (__float_as_uint(acc[rt][j]) & 0xFFFFFE00u)     \
                              | (unsigned)(baset - j);                        \
                float p = __uint_as_float(pv);                                \
                m2[rt] = fminf(fmaxf(p, m2[rt]), m1[rt]);                     \
                m1[rt] = fmaxf(p, m1[rt]);                                    \
            }                                                                 \
        }                                                                     \
    } while (0)

// fused scan + decide + quantized write. 512 threads: 8 waves = 4 row-quads
// x 2 k-halves. 256 rows per block. FOUR tiles per barrier; staging via
// global_load_lds (async direct-to-LDS).
__global__ __launch_bounds__(512) void vq_main(
    const float* __restrict__ x, const unsigned short* __restrict__ ehs,
    const float* __restrict__ neh, const float* __restrict__ emb,
    int N, int K,
    float* __restrict__ outq, float* __restrict__ outidx,
    double* __restrict__ lossA,
    unsigned* __restrict__ nunc, unsigned* __restrict__ list) {
    const int tid = threadIdx.x;
    const int lane = tid & 63;
    const int wid = tid >> 6;
    const int half = wid >> 2;           // k-slice 0/1
    const int wq = wid & 3;              // row quad
    const int rows0 = blockIdx.x * 256;
    const int row0 = rows0 + wq * 64;    // 64 rows/wave
    const int sub = lane & 15, grp = lane >> 4;
    const int g4 = grp << 2;
    const int k0 = half * (K >> 1);
    const int NT = (K >> 1) >> 4;        // 32 tiles per half
    const int t0 = k0 >> 4;

    // [half][buf][4 tiles x 2048 ush] = 64KB; grid gives 2 blocks/CU anyway
    __shared__ __align__(16) unsigned short lds[2][2][8192];
    __shared__ float sm1[2][256], sm2[2][256], sxx[256];
    __shared__ int sdec[256];
    __shared__ double ls[4];

    bf16x8 xh[4][2], xl[4][2];
    float xq[4];
#pragma unroll
    for (int rt = 0; rt < 4; ++rt) {
        xq[rt] = 0.f;
        const float* xrow = x + (((size_t)(row0 + (rt << 4) + sub)) << 6) + (grp << 3);
#pragma unroll
        for (int s = 0; s < 2; ++s) {
            float4 f0 = *(const float4*)(xrow + (s << 5));
            float4 f1 = *(const float4*)(xrow + (s << 5) + 4);
            xq[rt] = fmaf(f0.x, f0.x, xq[rt]); xq[rt] = fmaf(f0.y, f0.y, xq[rt]);
            xq[rt] = fmaf(f0.z, f0.z, xq[rt]); xq[rt] = fmaf(f0.w, f0.w, xq[rt]);
            xq[rt] = fmaf(f1.x, f1.x, xq[rt]); xq[rt] = fmaf(f1.y, f1.y, xq[rt]);
            xq[rt] = fmaf(f1.z, f1.z, xq[rt]); xq[rt] = fmaf(f1.w, f1.w, xq[rt]);
            CVT8(f0, f1, xh[rt][s], xl[rt][s]);
        }
    }
#pragma unroll
    for (int rt = 0; rt < 4; ++rt) {
        xq[rt] += __shfl_xor(xq[rt], 16);
        xq[rt] += __shfl_xor(xq[rt], 32);  // lane<16 holds full row xx
    }

    float m1[4], m2[4];
#pragma unroll
    for (int rt = 0; rt < 4; ++rt) { m1[rt] = -3e38f; m2[rt] = -3e38f; }

    const unsigned short* sbase = ehs + ((size_t)t0 << 11);  // 2048 ush/tile
    const int slot = (wq << 9) + (lane << 3);                // ushort offset
    const int wbase = wq << 9;           // wave-uniform LDS ushort offset

    // prologue: stage tiles 0..3 into buf 0 (async direct-to-LDS)
#pragma unroll
    for (int q = 0; q < 4; ++q)
        GLL16(sbase + ((size_t)q << 11) + slot,
              &lds[half][0][(q << 11) + wbase]);
    __syncthreads();

    for (int t = 0; t < NT; t += 4) {
        const int cur = (t >> 2) & 1;
        if (t + 4 < NT) {  // T14: issue next-quad async loads before compute
#pragma unroll
            for (int q = 0; q < 4; ++q)
                GLL16(sbase + ((size_t)(t + 4 + q) << 11) + slot,
                      &lds[half][cur ^ 1][(q << 11) + wbase]);
        }
        const bf16x8* L0 = (const bf16x8*)&lds[half][cur][0];
        const bf16x8* L1 = (const bf16x8*)&lds[half][cur][2048];
        const bf16x8* L2 = (const bf16x8*)&lds[half][cur][4096];
        const bf16x8* L3 = (const bf16x8*)&lds[half][cur][6144];
        TILE_STEP(L0, t);
        TILE_STEP(L1, t + 1);
        TILE_STEP(L2, t + 2);
        TILE_STEP(L3, t + 3);
        __syncthreads();  // drains vmcnt: next-quad loads complete
    }

    // merge the 4 code-groups: pure min/max on packed values
#pragma unroll
    for (int rt = 0; rt < 4; ++rt) {
#pragma unroll
        for (int off = 16; off <= 32; off <<= 1) {
            float om1 = __shfl_xor(m1[rt], off);
            float om2 = __shfl_xor(m2[rt], off);
            float lo = fminf(m1[rt], om1);
            m1[rt] = fmaxf(m1[rt], om1);
            m2[rt] = fmaxf(lo, fmaxf(m2[rt], om2));
        }
    }

    // per-half results -> LDS (lanes 0-15 own 16 consecutive rows per rt)
    if (lane < 16) {
#pragma unroll
        for (int rt = 0; rt < 4; ++rt) {
            int lr = wq * 64 + (rt << 4) + lane;
            sm1[half][lr] = m1[rt];
            sm2[half][lr] = m2[rt];
            if (half == 0) sxx[lr] = xq[rt];
        }
    }
    __syncthreads();

    // decide: waves 0-3, thread lr<256 merges the two halves for local row lr
    if (tid < 256) {
        const int lr = tid;
        const int r = rows0 + lr;
        float m1a = sm1[0][lr], m1b = sm1[1][lr];
        float m2a = sm2[0][lr], m2b = sm2[1][lr];
        bool take = m1b > m1a;  // strict: equal high-bit ties -> MARGIN band
        float gm1 = fmaxf(m1a, m1b);
        float gm2 = fmaxf(fminf(m1a, m1b), fmaxf(m2a, m2b));
        int loc = 511 - (int)(__float_as_uint(gm1) & 511u);
        int k = (take ? (K >> 1) : 0) + loc;
        bool amb = 2.0f * (gm1 - gm2) < MARGIN;
        unsigned long long mask = __ballot(amb);
        int cnt = __popcll(mask);
        unsigned base = 0;
        if (lane == 0 && cnt) base = atomicAdd(nunc, (unsigned)cnt);
        base = __shfl(base, 0);
        int dec = k;
        double lpart = 0.0;
        if (amb) {
            int rank = __popcll(mask & ((1ull << lane) - 1ull));
            list[base + rank] = (unsigned)r;
            dec = -1;
        } else {
            outidx[r] = (float)dec;
            // strip 9 packed index bits, then ||x-e||^2 = xx - 2*m1
            float gm1v = __uint_as_float(__float_as_uint(gm1) & 0xFFFFFE00u);
            lpart = (double)(sxx[lr] - 2.0f * gm1v);
        }
        sdec[lr] = dec;
#pragma unroll
        for (int off = 32; off; off >>= 1) lpart += __shfl_down(lpart, off);
        if (lane == 0) ls[wid] = lpart;
    }
    __syncthreads();
    if (tid == 0)
        lossA[blockIdx.x] = ls[0] + ls[1] + ls[2] + ls[3];  // plain store

    // quantized gather-write: 512 threads, wave-contiguous 1KB per pass
    const int chunk = tid & 15, rl = tid >> 4;  // 32 rows x 16 chunks
#pragma unroll
    for (int p = 0; p < 8; ++p) {
        int lr = p * 32 + rl;
        int dp = sdec[lr];
        if (dp >= 0) {
            float4 ev = *(const float4*)(emb + (size_t)dp * D + chunk * 4);
            *(float4*)(outq + (size_t)(rows0 + lr) * D + chunk * 4) = ev;
        }
    }
}

// batched np-f32-exact resolve: RB rows per block-pass share one eT stream
__global__ __launch_bounds__(256) void vq_resolve(
    const float* __restrict__ x, const float* __restrict__ emb,
    const float* __restrict__ eT, const float* __restrict__ eenp,
    int N, int K,
    float* __restrict__ outq, float* __restrict__ outidx,
    double* __restrict__ lossR,
    const unsigned* __restrict__ nunc, const unsigned* __restrict__ list) {
    const unsigned n = *nunc;
    const int tid = threadIdx.x;
    const int w = tid >> 6, l = tid & 63;
    const f32x4* eT4 = (const f32x4*)eT;  // [D][K/4]
    __shared__ float sxr[RB][64];
    __shared__ float sxx[RB];
    __shared__ float swm[RB][4];
    __shared__ int swi[RB][4];
    __shared__ int sres[RB];
    double lacc = 0.0;

    for (unsigned base = blockIdx.x * RB; base < n; base += gridDim.x * RB) {
        const int nb = (int)(n - base < (unsigned)RB ? n - base : (unsigned)RB);
#pragma unroll
        for (int i = tid; i < RB * 64; i += 256) {
            int r = i >> 6, d = i & 63;
            if (r < nb) sxr[r][d] = x[(size_t)list[base + r] * D + d];
        }
        __syncthreads();
        if (tid < nb) sxx[tid] = np_pairwise_sumsq64(&sxr[tid][0]);
        __syncthreads();

        f32x4 dt[RB];
#pragma unroll
        for (int r = 0; r < RB; ++r) dt[r] = (f32x4){0.f, 0.f, 0.f, 0.f};
#pragma unroll 4
        for (int d = 0; d < D; ++d) {
            f32x4 ev = eT4[(size_t)d * 256 + tid];
#pragma unroll
            for (int r = 0; r < RB; ++r) {
                float xv = sxr[r][d];
                dt[r][0] = __fmaf_rn(xv, ev[0], dt[r][0]);
                dt[r][1] = __fmaf_rn(xv, ev[1], dt[r][1]);
                dt[r][2] = __fmaf_rn(xv, ev[2], dt[r][2]);
                dt[r][3] = __fmaf_rn(xv, ev[3], dt[r][3]);
            }
        }

#pragma unroll
        for (int r = 0; r < RB; ++r) {
            if (r >= nb) break;
            float xx = sxx[r];
            float bm = 1e30f;
            int bi = 0;
#pragma unroll
            for (int jj = 0; jj < 4; ++jj) {
                int k = (tid << 2) + jj;  // ascending within thread
                float dist = __fsub_rn(__fadd_rn(xx, eenp[k]),
                                       __fmul_rn(2.0f, dt[r][jj]));
                if (dist < bm) { bm = dist; bi = k; }
            }
#pragma unroll
            for (int off = 1; off < 64; off <<= 1) {
                float ov = __shfl_xor(bm, off);
                int oi = __shfl_xor(bi, off);
                if (ov < bm || (ov == bm && oi < bi)) { bm = ov; bi = oi; }
            }
            if (l == 0) { swm[r][w] = bm; swi[r][w] = bi; }
        }
        __syncthreads();
        if (tid < nb) {  // thread r finalizes row r (ascending wave order)
            float fm = swm[tid][0];
            int fi = swi[tid][0];
#pragma unroll
            for (int ww = 1; ww < 4; ++ww) {
                float ov = swm[tid][ww];
                int oi = swi[tid][ww];
                if (ov < fm || (ov == fm && oi < fi)) { fm = ov; fi = oi; }
            }
            sres[tid] = fi;
            outidx[list[base + tid]] = (float)fi;
            lacc += (double)fm;
        }
        __syncthreads();
        for (int i = tid; i < RB * 64; i += 256) {
            int r = i >> 6, d = i & 63;
            if (r < nb)
                outq[(size_t)list[base + r] * D + d] =
                    emb[(size_t)sres[r] * D + d];
        }
        __syncthreads();
    }
#pragma unroll
    for (int off = 32; off; off >>= 1) lacc += __shfl_down(lacc, off);
    __shared__ double lsw;
    if (tid == 0) lsw = lacc;
    __syncthreads();
    if (tid == 0) lossR[blockIdx.x] = lsw;
}

// histogram of outidx via LDS (16 fat blocks) + last-block finalize
__global__ __launch_bounds__(256) void vq_histperp(
    const float* __restrict__ outidx, int N, int K,
    unsigned* __restrict__ counts, unsigned* __restrict__ done,
    const double* __restrict__ lossA, int nA,
    const double* __restrict__ lossR, int nR,
    float* __restrict__ out_loss, float* __restrict__ out_perp) {
    __shared__ unsigned h[1024];
    __shared__ unsigned rank_s;
#pragma unroll
    for (int i = 0; i < 4; ++i) h[threadIdx.x + 256 * i] = 0;
    __syncthreads();
    int per = N / gridDim.x;
    int base = blockIdx.x * per;
    for (int i = threadIdx.x; i < per; i += 256) {
        int k = (int)outidx[base + i];
        atomicAdd(&h[k], 1u);
    }
    __syncthreads();
#pragma unroll
    for (int i = 0; i < 4; ++i) {
        int b = threadIdx.x + 256 * i;
        unsigned v = h[b];
        if (b < K && v) atomicAdd(counts + b, v);
    }
    __threadfence();
    if (threadIdx.x == 0) rank_s = atomicAdd(done, 1u);
    __syncthreads();
    if (rank_s == gridDim.x - 1) {  // last block: counts complete
        double part = 0.0;
        for (int k = threadIdx.x; k < K; k += 256) {
            unsigned c = atomicAdd(counts + k, 0u);  // device-scope read
            double p = (double)c / (double)N;
            part += p * log(p + 1e-10);
        }
        double lsum = 0.0;
        for (int i = threadIdx.x; i < nA; i += 256) lsum += lossA[i];
        for (int i = threadIdx.x; i < nR; i += 256) lsum += lossR[i];
#pragma unroll
        for (int off = 32; off; off >>= 1) {
            part += __shfl_down(part, off);
            lsum += __shfl_down(lsum, off);
        }
        __shared__ double ls[4], ls2[4];
        if ((threadIdx.x & 63) == 0) {
            ls[threadIdx.x >> 6] = part;
            ls2[threadIdx.x >> 6] = lsum;
        }
        __syncthreads();
        if (threadIdx.x == 0) {
            double s = ls[0] + ls[1] + ls[2] + ls[3];
            double L = ls2[0] + ls2[1] + ls2[2] + ls2[3];
            *out_perp = (float)exp(-s);
            *out_loss = (float)(1.25 * (L / ((double)N * (double)D)));
        }
    }
}

extern "C" void kernel_launch(void* const* d_in, const int* in_sizes, int n_in,
                              void* d_out, int out_size, void* d_ws, size_t ws_size,
                              hipStream_t stream) {
    const float* x = (const float*)d_in[0];
    const float* emb = (const float*)d_in[1];
    int N = in_sizes[0] / D;
    int K = in_sizes[1] / D;

    float* outq = (float*)d_out;
    float* out_loss = outq + (size_t)N * D;
    float* outidx = out_loss + 1;
    float* out_perp = outidx + N;

    char* ws = (char*)d_ws;
    unsigned* counts = (unsigned*)ws;                          // K*4
    unsigned* done = (unsigned*)(ws + (size_t)K * 4);          // 4
    unsigned* nunc = (unsigned*)(ws + (size_t)K * 4 + 4);      // 4 (+8 pad)
    size_t off = (size_t)K * 4 + 16;
    float* neh = (float*)(ws + off);            off += (size_t)K * 4;
    float* eenp = (float*)(ws + off);           off += (size_t)K * 4;
    unsigned short* ehs = (unsigned short*)(ws + off);  off += (size_t)K * 256;
    float* eT = (float*)(ws + off);              off += (size_t)K * D * 4;
    unsigned* list = (unsigned*)(ws + off);      off += (size_t)N * 4;
    int nA = N / 256, nR = 128;
    double* lossA = (double*)(ws + off);         off += (size_t)nA * 8;
    double* lossR = (double*)(ws + off);         off += (size_t)nR * 8;

    // prep: 64 ehs + 4 sums + 256 eT + 1 zero-counters = 325 blocks
    vq_prep_all<<<325, 256, 0, stream>>>(emb, K, eenp, neh, ehs, eT,
                                         counts, done, nunc);
    vq_main<<<N / 256, 512, 0, stream>>>(x, ehs, neh, emb, N, K,
                                         outq, outidx, lossA, nunc, list);
    vq_resolve<<<128, 256, 0, stream>>>(x, emb, eT, eenp, N, K,
                                        outq, outidx, lossR, nunc, list);
    vq_histperp<<<16, 256, 0, stream>>>(outidx, N, K, counts, done,
                                        lossA, nA, lossR, nR,
                                        out_loss, out_perp);
}